// Round 9
// baseline (294.875 us; speedup 1.0000x reference)
//
#include <hip/hip_runtime.h>
#include <cstdint>
#include <cstddef>

#define D_MODEL 2048
#define T_SEQ   2048
#define BATCH   2
#define N_HEADS 16
#define KV_HEADS 4
#define HEAD_DIM 128
#define QKV_N   3072          // D_MODEL + 2*512
#define ROWS    (BATCH * T_SEQ) // 4096

typedef float  floatx4 __attribute__((ext_vector_type(4)));
typedef short  shortx8 __attribute__((ext_vector_type(8)));
typedef __bf16 bf16x8  __attribute__((ext_vector_type(8)));

typedef const void __attribute__((address_space(1))) gvoid_t;
typedef void __attribute__((address_space(3)))       svoid_t;

__device__ __forceinline__ floatx4 mfma16(shortx8 a, shortx8 b, floatx4 c) {
  return __builtin_amdgcn_mfma_f32_16x16x32_bf16(
      __builtin_bit_cast(bf16x8, a), __builtin_bit_cast(bf16x8, b), c, 0, 0, 0);
}

__device__ __forceinline__ unsigned short f2bf(float f) {
  union { float f; unsigned int u; } v; v.f = f;
  unsigned int u = v.u;
  u += 0x7fffu + ((u >> 16) & 1u);   // RNE
  return (unsigned short)(u >> 16);
}

// native RNE cast — compiler emits v_cvt_pk_bf16_f32 for pairs (hot paths)
__device__ __forceinline__ unsigned short f2bf_hw(float f) {
  return __builtin_bit_cast(unsigned short, (__bf16)f);
}

// pack two f32 -> u32 of 2 bf16 (compiler fuses to v_cvt_pk_bf16_f32)
__device__ __forceinline__ unsigned int pk2bf(float lo, float hi) {
  return (unsigned int)f2bf_hw(lo) | ((unsigned int)f2bf_hw(hi) << 16);
}

// ---------------- fused prep: cvt_x + transpose(qkv_w) + transpose(proj_w) ----
__global__ __launch_bounds__(256) void prep_kernel(
    const float* __restrict__ x, unsigned short* __restrict__ x_bf,
    const float* __restrict__ qkv_w, unsigned short* __restrict__ qkvw_t,
    const float* __restrict__ proj_w, unsigned short* __restrict__ projw_t)
{
  __shared__ float tile[32][33];
  const int bid = blockIdx.x, tid = threadIdx.x;
  if (bid < 8192) {                       // x: fp32 -> bf16, 4 elems/thread
    const int i = bid * 256 + tid;
    float4 v = ((const float4*)x)[i];
    ushort4 o;
    o.x = f2bf(v.x); o.y = f2bf(v.y); o.z = f2bf(v.z); o.w = f2bf(v.w);
    ((ushort4*)x_bf)[i] = o;
    return;
  }
  const float* W; unsigned short* Wt; int N, bx, by;
  if (bid < 14336) { const int v = bid - 8192;  W = qkv_w;  Wt = qkvw_t;  N = QKV_N;   bx = v % 96; by = v / 96; }
  else             { const int v = bid - 14336; W = proj_w; Wt = projw_t; N = D_MODEL; bx = v % 64; by = v / 64; }
  const int K = D_MODEL;
  const int n0 = bx * 32, k0 = by * 32;
  const int tx = tid & 31, ty = tid >> 5;   // (32, 8)
  #pragma unroll
  for (int i = 0; i < 32; i += 8)
    tile[ty + i][tx] = W[(size_t)(k0 + ty + i) * N + n0 + tx];
  __syncthreads();
  #pragma unroll
  for (int i = 0; i < 32; i += 8)
    Wt[(size_t)(n0 + ty + i) * K + k0 + tx] = f2bf(tile[tx][ty + i]);
}

// ------- 256-row x (NB*128)-col 8-phase bf16 GEMM: C = A * Bt^T + bias ---------
// NB=2: BN=256, LDS 128K, vmcnt(6). NB=1: BN=128, LDS 96K, vmcnt(4).
// T1 XCD swizzle: hardware block f -> work (f&7)*cpx + (f>>3); each XCD gets a
// contiguous chunk of output tiles -> shared A/B panels stay in its 4MB L2.
// cmode 0: C = f32[M][N]. cmode 2: fused QKV epilogue (Q compact / kst / vst
// with sigma key-permutation for attn's lane-local PV).
template<int NB>
__global__ __launch_bounds__(512, 2) void gemm256(
    const unsigned short* __restrict__ A,
    const unsigned short* __restrict__ Bt,
    const float* __restrict__ bias,
    void* __restrict__ Cout,
    unsigned short* __restrict__ kst,
    unsigned short* __restrict__ vst,
    int M, int N, int K, int cmode)
{
  __shared__ __align__(16) unsigned short lds[32768 + NB * 16384];
  const int tid  = threadIdx.x;
  const int wave = tid >> 6, lane = tid & 63;
  const int quad = lane >> 4, l16 = lane & 15;
  const int wr = wave >> 2, wc = wave & 3;        // 2 x 4 wave grid

  // T1 bijective XCD swizzle (nwg % 8 == 0 for all our grids)
  const int nwg = gridDim.x * gridDim.y;
  const int cpx = nwg >> 3;
  const int f   = blockIdx.y * gridDim.x + blockIdx.x;
  const int w   = (f & 7) * cpx + (f >> 3);
  const int bm  = (w / gridDim.x) * 256;
  const int bn  = (w % gridDim.x) * (NB * 128);
  const int NT = K >> 6;                          // 64-wide K tiles

  const int r0 = tid >> 3;                        // row 0..63 (j=0)
  const int cx = (tid & 7) ^ (r0 & 7);            // inverse swizzle of k-chunk
  const size_t K64 = (size_t)64 * K;              // 64 rows worth of elements
  const unsigned short* a_src = A  + (size_t)(bm + r0) * K + cx * 8;
  const unsigned short* b_src = Bt + (size_t)(bn + r0) * K + cx * 8;
  const int wOff = wave * 512;                    // wave-uniform LDS offset (elems)

  #define LDSA_(buf, half) (lds + (((buf) << 1) + (half)) * 8192)
  #define LDSB_(buf, half) (lds + 32768 + (((buf) << 1) + (half)) * (NB * 4096))
  #define KOFFA(h, t) ((size_t)(h) * 128 * K + (size_t)(t) * 64)
  #define KOFFB(h, t) ((size_t)(h) * (64 * NB) * K + (size_t)(t) * 64)
  #define STAGE_A(srcbase, ldshalf, koff) do {                                        \
    __builtin_amdgcn_global_load_lds((gvoid_t*)((srcbase) + (koff)),                  \
        (svoid_t*)((ldshalf) + wOff), 16, 0, 0);                                      \
    __builtin_amdgcn_global_load_lds((gvoid_t*)((srcbase) + (koff) + K64),            \
        (svoid_t*)((ldshalf) + wOff + 4096), 16, 0, 0);                               \
  } while (0)
  #define STAGE_B(srcbase, ldshalf, koff) do {                                        \
    _Pragma("unroll")                                                                 \
    for (int j_ = 0; j_ < NB; ++j_)                                                   \
      __builtin_amdgcn_global_load_lds(                                               \
          (gvoid_t*)((srcbase) + (koff) + (size_t)j_ * K64),                          \
          (svoid_t*)((ldshalf) + wOff + j_ * 4096), 16, 0, 0);                        \
  } while (0)

  const int rowA = (wr * 64 + l16) * 64;          // within half-tile, elems
  const int rowB = (wc * (16 * NB) + l16) * 64;
  const int xo0 = ((quad)     ^ (l16 & 7)) * 8;   // ks=0 chunk
  const int xo1 = ((4 + quad) ^ (l16 & 7)) * 8;   // ks=1 chunk

  floatx4 acc[8][2 * NB] = {};
  shortx8 Afr[4][2];
  shortx8 Bfr[2 * NB][2];

  STAGE_A(a_src, LDSA_(0, 0), KOFFA(0, 0));
  STAGE_B(b_src, LDSB_(0, 0), KOFFB(0, 0));
  STAGE_B(b_src, LDSB_(0, 1), KOFFB(1, 0));
  STAGE_A(a_src, LDSA_(0, 1), KOFFA(1, 0));
  if (NT > 1) {
    STAGE_A(a_src, LDSA_(1, 0), KOFFA(0, 1));
    STAGE_B(b_src, LDSB_(1, 0), KOFFB(0, 1));
    STAGE_B(b_src, LDSB_(1, 1), KOFFB(1, 1));
  }

  for (int t = 0; t < NT; ++t) {
    const int buf = t & 1;
    unsigned short* sA0 = LDSA_(buf, 0);
    unsigned short* sA1 = LDSA_(buf, 1);
    unsigned short* sB0 = LDSB_(buf, 0);
    unsigned short* sB1 = LDSB_(buf, 1);

    // ---- phase 0 ----
    if (t == NT - 1) asm volatile("s_waitcnt vmcnt(0)" ::: "memory");
    else if constexpr (NB == 2) asm volatile("s_waitcnt vmcnt(6)" ::: "memory");
    else                        asm volatile("s_waitcnt vmcnt(4)" ::: "memory");
    __builtin_amdgcn_s_barrier();
    #pragma unroll
    for (int mi = 0; mi < 4; ++mi) {
      Afr[mi][0] = *(const shortx8*)(sA0 + rowA + mi * 1024 + xo0);
      Afr[mi][1] = *(const shortx8*)(sA0 + rowA + mi * 1024 + xo1);
    }
    #pragma unroll
    for (int ni = 0; ni < NB; ++ni) {
      Bfr[ni][0] = *(const shortx8*)(sB0 + rowB + ni * 1024 + xo0);
      Bfr[ni][1] = *(const shortx8*)(sB0 + rowB + ni * 1024 + xo1);
    }
    if (t + 1 < NT) STAGE_A(a_src, LDSA_(buf ^ 1, 1), KOFFA(1, t + 1));
    asm volatile("s_waitcnt lgkmcnt(0)" ::: "memory");
    __builtin_amdgcn_s_setprio(1);
    #pragma unroll
    for (int ks = 0; ks < 2; ++ks)
      #pragma unroll
      for (int mi = 0; mi < 4; ++mi)
        #pragma unroll
        for (int ni = 0; ni < NB; ++ni)
          acc[mi][ni] = mfma16(Afr[mi][ks], Bfr[ni][ks], acc[mi][ni]);
    __builtin_amdgcn_s_setprio(0);
    __builtin_amdgcn_s_barrier();

    // ---- phase 1 ----
    #pragma unroll
    for (int ni = 0; ni < NB; ++ni) {
      Bfr[NB + ni][0] = *(const shortx8*)(sB1 + rowB + ni * 1024 + xo0);
      Bfr[NB + ni][1] = *(const shortx8*)(sB1 + rowB + ni * 1024 + xo1);
    }
    if (t + 2 < NT) STAGE_A(a_src, LDSA_(buf, 0), KOFFA(0, t + 2));
    __builtin_amdgcn_s_barrier();
    asm volatile("s_waitcnt lgkmcnt(0)" ::: "memory");
    __builtin_amdgcn_s_setprio(1);
    #pragma unroll
    for (int ks = 0; ks < 2; ++ks)
      #pragma unroll
      for (int mi = 0; mi < 4; ++mi)
        #pragma unroll
        for (int ni = 0; ni < NB; ++ni)
          acc[mi][NB + ni] = mfma16(Afr[mi][ks], Bfr[NB + ni][ks], acc[mi][NB + ni]);
    __builtin_amdgcn_s_setprio(0);
    __builtin_amdgcn_s_barrier();

    // ---- phase 2 ----
    #pragma unroll
    for (int mi = 0; mi < 4; ++mi) {
      Afr[mi][0] = *(const shortx8*)(sA1 + rowA + mi * 1024 + xo0);
      Afr[mi][1] = *(const shortx8*)(sA1 + rowA + mi * 1024 + xo1);
    }
    if (t + 2 < NT) STAGE_B(b_src, LDSB_(buf, 0), KOFFB(0, t + 2));
    __builtin_amdgcn_s_barrier();
    asm volatile("s_waitcnt lgkmcnt(0)" ::: "memory");
    __builtin_amdgcn_s_setprio(1);
    #pragma unroll
    for (int ks = 0; ks < 2; ++ks)
      #pragma unroll
      for (int mi = 0; mi < 4; ++mi)
        #pragma unroll
        for (int ni = 0; ni < NB; ++ni)
          acc[4 + mi][NB + ni] = mfma16(Afr[mi][ks], Bfr[NB + ni][ks], acc[4 + mi][NB + ni]);
    __builtin_amdgcn_s_setprio(0);
    __builtin_amdgcn_s_barrier();

    // ---- phase 3 ----
    if (t + 2 < NT) STAGE_B(b_src, LDSB_(buf, 1), KOFFB(1, t + 2));
    __builtin_amdgcn_s_barrier();
    __builtin_amdgcn_s_setprio(1);
    #pragma unroll
    for (int ks = 0; ks < 2; ++ks)
      #pragma unroll
      for (int mi = 0; mi < 4; ++mi)
        #pragma unroll
        for (int ni = 0; ni < NB; ++ni)
          acc[4 + mi][ni] = mfma16(Afr[mi][ks], Bfr[ni][ks], acc[4 + mi][ni]);
    __builtin_amdgcn_s_setprio(0);
    __builtin_amdgcn_s_barrier();
  }

  #pragma unroll
  for (int mi = 0; mi < 8; ++mi) {
    const int row = bm + (mi >> 2) * 128 + wr * 64 + (mi & 3) * 16 + quad * 4;
    #pragma unroll
    for (int ni = 0; ni < 2 * NB; ++ni) {
      const int col = bn + (ni / NB) * (64 * NB) + wc * (16 * NB) + (ni % NB) * 16 + l16;
      const float bv = bias[col];
      #pragma unroll
      for (int r = 0; r < 4; ++r) {
        float v = acc[mi][ni][r] + bv;
        if (cmode == 0) {
          ((float*)Cout)[(size_t)(row + r) * N + col] = v;
        } else {
          const unsigned short h = f2bf_hw(v);
          const int rw = row + r;
          const int t = rw & 2047, bb = rw >> 11;
          if (col < 2048) {
            ((unsigned short*)Cout)[(size_t)rw * 2048 + col] = h;
          } else if (col < 2560) {
            // K staged: [b][kvh][d8][t][8]
            const int c2 = col - 2048, kvh = c2 >> 7, d = c2 & 127;
            kst[((((size_t)bb * 4 + kvh) * 16 + (d >> 3)) * 2048 + t) * 8 + (d & 7)] = h;
          } else {
            // V staged: [b][kvh][t8'][d][8] with sigma key-permutation:
            // slot ts = (t&~31) | ((t>>2)&3)<<3 | ((t>>4)&1)<<2 | (t&3)
            const int c2 = col - 2560, kvh = c2 >> 7, d = c2 & 127;
            const int ts = (t & ~31) | (((t >> 2) & 3) << 3) | (((t >> 4) & 1) << 2) | (t & 3);
            vst[((((size_t)bb * 4 + kvh) * 256 + (ts >> 3)) * 128 + d) * 8 + (ts & 7)] = h;
          }
        }
      }
    }
  }
  #undef LDSA_
  #undef LDSB_
  #undef KOFFA
  #undef KOFFB
  #undef STAGE_A
  #undef STAGE_B
}

// ---------------- flash attention, GQA, causal — swapped-QK in-register softmax
// grid (16, N_HEADS, B) = 512 blocks x 512 threads; wave = (split, rowgroup).
// T1 XCD swizzle: hardware block f -> work (f&7)*64 + (f>>3); each XCD owns
// exactly one (b, kvh) group (64 blocks) -> its 1 MB K/V set stays L2-resident.
// st = mfma(K,Q); scalar m/l per lane, P packed in-register, PV via
// sigma-permuted V. LDS 64 KB -> 2 blocks/CU = 4 waves/SIMD.
__global__ __launch_bounds__(512, 4) void attn_kernel(
    const unsigned short* __restrict__ qbuf,  // (B*T, 2048) bf16 Q
    const unsigned short* __restrict__ kst,   // [b][kvh][d8][t][8]
    const unsigned short* __restrict__ vst,   // [b][kvh][t8'][d][8] (sigma-permuted)
    unsigned short* __restrict__ aout)        // (B*T, D_MODEL) bf16
{
  __shared__ __align__(16) unsigned short sK[2][16 * 64 * 8];   // per split [d8][key][8]
  __shared__ __align__(16) unsigned short sV[2][8 * 128 * 8];   // per split [t8'][d][8]

  const int tid  = threadIdx.x;
  const int wave = tid >> 6, lane = tid & 63;
  const int split = wave >> 2, g = wave & 3;
  const int quad = lane >> 4, l16 = lane & 15;

  // T1 bijective XCD swizzle over the 512-block grid
  const int f = blockIdx.x + (blockIdx.y << 4) + (blockIdx.z << 8);
  const int w = ((f & 7) << 6) + (f >> 3);
  const int bxw = w & 15, head = (w >> 4) & 15, b = w >> 8;

  const int kvh = head >> 2;
  const float cf = 0.08838834764831845f * 1.4426950408889634f;  // scale*log2e
  const float THR = 25.0f;  // defer-max threshold (raw S units)

  const unsigned short* kbase = kst + (size_t)((b * KV_HEADS + kvh) * 16) * 2048 * 8;
  const unsigned short* vbase = vst + (size_t)((b * KV_HEADS + kvh) * 256) * 128 * 8;

  // merge scratch overlays K/V LDS (used only after the kt loop, post-barrier)
  float* mrgO  = (float*)&sK[0][0];   // [g][d=128][q=16] f32 = 32 KB
  float* mrgML = (float*)&sV[0][0];   // [g][lane][{m,l}] f32 = 2 KB

  #define STAGE_KV(sp, kb_) do {                                               \
    _Pragma("unroll")                                                          \
    for (int it_ = 0; it_ < 4; ++it_) {                                        \
      const int c_ = it_ * 4 + g;                                              \
      __builtin_amdgcn_global_load_lds(                                        \
          (gvoid_t*)(kbase + ((size_t)c_ * 2048 + (kb_)) * 8 + lane * 8),      \
          (svoid_t*)(&sK[sp][c_ * 512]), 16, 0, 0);                            \
    }                                                                          \
    const unsigned short* vt_ = vbase + (size_t)((kb_) >> 3) * 128 * 8;        \
    _Pragma("unroll")                                                          \
    for (int it_ = 0; it_ < 4; ++it_) {                                        \
      const int c_ = it_ * 4 + g;                                              \
      __builtin_amdgcn_global_load_lds(                                        \
          (gvoid_t*)(vt_ + c_ * 512 + lane * 8),                               \
          (svoid_t*)(&sV[sp][c_ * 512]), 16, 0, 0);                            \
    }                                                                          \
  } while (0)

  #pragma unroll 1
  for (int half = 0; half < 2; ++half) {
    const int qt = half ? bxw : (31 - bxw);
    const int q0 = qt * 64;

    // Q fragments (query = q0 + g*16 + l16; B-operand role)
    shortx8 qf[4];
    {
      const unsigned short* qp = qbuf + (size_t)(b * T_SEQ + q0 + g * 16 + l16) * 2048
                                 + head * HEAD_DIM + quad * 8;
      #pragma unroll
      for (int ks = 0; ks < 4; ++ks)
        qf[ks] = *(const shortx8*)(qp + ks * 32);
    }

    float m_i = -__builtin_inff(), l_i = 0.f;
    floatx4 o_acc[8] = {};   // [nt]: O[query=l16][d = nt*16 + quad*4 + r]

    const int J = (qt >> 1) + 1;   // ceil((qt+1)/2)
    for (int j = 0; j < J; ++j) {
      const int kt = 2 * j + split;
      const bool act = (kt <= qt);
      floatx4 st[4] = {};          // st[ct][r] = S[query=l16][key=kt*64+ct*16+quad*4+r]
      unsigned int pk[4][2];       // packed bf16 P, 2 u32 per ct

      __builtin_amdgcn_s_barrier();   // A: prev iteration's LDS reads complete
      if (act) STAGE_KV(split, kt * 64);
      asm volatile("s_waitcnt vmcnt(4)" ::: "memory");  // K written; V in flight
      __builtin_amdgcn_s_barrier();   // B: K tile visible to the split's waves

      if (act) {
        // S^T = K Q^T (swapped operands; same fragments)
        __builtin_amdgcn_s_setprio(1);
        #pragma unroll
        for (int ks = 0; ks < 4; ++ks) {
          #pragma unroll
          for (int ct = 0; ct < 4; ++ct) {
            shortx8 kf = *(const shortx8*)&sK[split][((ks * 4 + quad) * 64 + ct * 16 + l16) * 8];
            st[ct] = mfma16(kf, qf[ks], st[ct]);
          }
        }
        __builtin_amdgcn_s_setprio(0);

        // causal mask on the diagonal tile
        if (kt == qt) {
          const int qrow = q0 + g * 16 + l16;
          const int kb = kt * 64;
          #pragma unroll
          for (int ct = 0; ct < 4; ++ct) {
            #pragma unroll
            for (int r = 0; r < 4; ++r)
              if (kb + ct * 16 + quad * 4 + r > qrow) st[ct][r] = -__builtin_inff();
          }
        }

        // local 16-max; defer-max: full 2-shuffle reduce only when triggered
        float lmx = -__builtin_inff();
        #pragma unroll
        for (int ct = 0; ct < 4; ++ct)
          lmx = fmaxf(lmx, fmaxf(fmaxf(st[ct][0], st[ct][1]), fmaxf(st[ct][2], st[ct][3])));
        if (__ballot(lmx > m_i + THR)) {
          float m = lmx;
          m = fmaxf(m, __shfl_xor(m, 16));
          m = fmaxf(m, __shfl_xor(m, 32));
          const float newm = fmaxf(m_i, m);
          const float alpha = exp2f((m_i - newm) * cf);
          m_i = newm;
          l_i *= alpha;
          #pragma unroll
          for (int nt = 0; nt < 8; ++nt)
            #pragma unroll
            for (int r = 0; r < 4; ++r) o_acc[nt][r] *= alpha;
        }

        // P = exp2((S - m)*cf); accumulate partial l; pack to bf16 in-register
        const float nmc = m_i * cf;
        float ps = 0.f;
        #pragma unroll
        for (int ct = 0; ct < 4; ++ct) {
          #pragma unroll
          for (int r = 0; r < 4; ++r) {
            st[ct][r] = exp2f(fmaf(st[ct][r], cf, -nmc));
            ps += st[ct][r];
          }
          pk[ct][0] = pk2bf(st[ct][0], st[ct][1]);
          pk[ct][1] = pk2bf(st[ct][2], st[ct][3]);
        }
        l_i += ps;
      }

      asm volatile("s_waitcnt vmcnt(0)" ::: "memory");  // own V writes done
      __builtin_amdgcn_s_barrier();   // C: V tile visible

      if (act) {
        // O^T += V^T P^T : A = vf (d rows), B = pa (lane-local packed P)
        #pragma unroll
        for (int kc = 0; kc < 2; ++kc) {
          union { unsigned int u[4]; shortx8 s; } pa;
          pa.u[0] = pk[2 * kc][0];     pa.u[1] = pk[2 * kc][1];
          pa.u[2] = pk[2 * kc + 1][0]; pa.u[3] = pk[2 * kc + 1][1];
          __builtin_amdgcn_s_setprio(1);
          #pragma unroll
          for (int nt = 0; nt < 8; ++nt) {
            shortx8 vf = *(const shortx8*)&sV[split][((kc * 4 + quad) * 128 + nt * 16 + l16) * 8];
            o_acc[nt] = mfma16(vf, pa.s, o_acc[nt]);
          }
          __builtin_amdgcn_s_setprio(0);
        }
      }
    }

    // ---- merge split partials, then epilogue (split0 finalizes) ----
    __builtin_amdgcn_s_barrier();   // all compute reads of K/V LDS done
    if (split == 1) {
      #pragma unroll
      for (int nt = 0; nt < 8; ++nt)
        #pragma unroll
        for (int r = 0; r < 4; ++r)
          mrgO[g * 2048 + (nt * 16 + quad * 4 + r) * 16 + l16] = o_acc[nt][r];
      mrgML[(g * 64 + lane) * 2]     = m_i;
      mrgML[(g * 64 + lane) * 2 + 1] = l_i;
    }
    asm volatile("s_waitcnt lgkmcnt(0)" ::: "memory");
    __builtin_amdgcn_s_barrier();   // partials visible

    if (split == 0) {
      const float m1 = mrgML[(g * 64 + lane) * 2];
      const float l1 = mrgML[(g * 64 + lane) * 2 + 1];
      const float M  = fmaxf(m_i, m1);
      const float a0 = exp2f((m_i - M) * cf);
      const float a1 = exp2f((m1 - M) * cf);
      float lm = a0 * l_i + a1 * l1;
      #pragma unroll
      for (int nt = 0; nt < 8; ++nt)
        #pragma unroll
        for (int r = 0; r < 4; ++r)
          o_acc[nt][r] = a0 * o_acc[nt][r]
                       + a1 * mrgO[g * 2048 + (nt * 16 + quad * 4 + r) * 16 + l16];

      lm += __shfl_xor(lm, 16);
      lm += __shfl_xor(lm, 32);
      const float inv = 1.f / lm;
      const size_t orow = (size_t)(b * T_SEQ + q0 + g * 16 + l16) * D_MODEL + head * HEAD_DIM;
      #pragma unroll
      for (int nt = 0; nt < 8; ++nt) {
        uint2 w2;
        w2.x = pk2bf(o_acc[nt][0] * inv, o_acc[nt][1] * inv);
        w2.y = pk2bf(o_acc[nt][2] * inv, o_acc[nt][3] * inv);
        *(uint2*)&aout[orow + nt * 16 + quad * 4] = w2;
      }
    }
  }
  #undef STAGE_KV
}

extern "C" void kernel_launch(void* const* d_in, const int* in_sizes, int n_in,
                              void* d_out, int out_size, void* d_ws, size_t ws_size,
                              hipStream_t stream) {
  const float* x      = (const float*)d_in[0];
  // d_in[1] = attn_mask (causal; unused)
  const float* qkv_w  = (const float*)d_in[2];
  const float* qkv_b  = (const float*)d_in[3];
  const float* proj_w = (const float*)d_in[4];
  const float* proj_b = (const float*)d_in[5];
  float* out = (float*)d_out;

  char* ws = (char*)d_ws;
  // workspace map (bytes):
  //   [0,16M)            x_bf (GEMM1 A), later attn_out
  //   [16M, 29.36M)      qkvw_t
  //   [29.36M, 37.75M)   projw_t
  //   [37.75M, 54.53M)   qbuf
  //   [54.53M, 58.72M)   kstaged
  //   [58.72M, 62.91M)   vstaged (sigma-permuted)
  unsigned short* x_bf    = (unsigned short*)(ws);
  unsigned short* qkvw_t  = (unsigned short*)(ws + (size_t)16777216);
  unsigned short* projw_t = (unsigned short*)(ws + (size_t)29360128);
  unsigned short* qbuf    = (unsigned short*)(ws + (size_t)37748736);
  unsigned short* kstaged = (unsigned short*)(ws + (size_t)54525952);
  unsigned short* vstaged = (unsigned short*)(ws + (size_t)58720256);
  unsigned short* attn_out = x_bf;   // safe alias: x_bf dead after GEMM1

  prep_kernel<<<18432, 256, 0, stream>>>(x, x_bf, qkv_w, qkvw_t, proj_w, projw_t);
  gemm256<2><<<dim3(QKV_N / 256, ROWS / 256), 512, 0, stream>>>(
      x_bf, qkvw_t, qkv_b, (void*)qbuf, kstaged, vstaged, ROWS, QKV_N, D_MODEL, 2);
  attn_kernel<<<dim3(16, N_HEADS, BATCH), 512, 0, stream>>>(qbuf, kstaged, vstaged, attn_out);
  gemm256<1><<<dim3(D_MODEL / 128, ROWS / 256), 512, 0, stream>>>(
      attn_out, projw_t, proj_b, (void*)out, nullptr, nullptr, ROWS, D_MODEL, D_MODEL, 0);
}

// Round 10
// 294.197 us; speedup vs baseline: 1.0023x; 1.0023x over previous
//
#include <hip/hip_runtime.h>
#include <cstdint>
#include <cstddef>

#define D_MODEL 2048
#define T_SEQ   2048
#define BATCH   2
#define N_HEADS 16
#define KV_HEADS 4
#define HEAD_DIM 128
#define QKV_N   3072          // D_MODEL + 2*512
#define ROWS    (BATCH * T_SEQ) // 4096

typedef float  floatx4 __attribute__((ext_vector_type(4)));
typedef short  shortx8 __attribute__((ext_vector_type(8)));
typedef __bf16 bf16x8  __attribute__((ext_vector_type(8)));

typedef const void __attribute__((address_space(1))) gvoid_t;
typedef void __attribute__((address_space(3)))       svoid_t;

__device__ __forceinline__ floatx4 mfma16(shortx8 a, shortx8 b, floatx4 c) {
  return __builtin_amdgcn_mfma_f32_16x16x32_bf16(
      __builtin_bit_cast(bf16x8, a), __builtin_bit_cast(bf16x8, b), c, 0, 0, 0);
}

__device__ __forceinline__ unsigned short f2bf(float f) {
  union { float f; unsigned int u; } v; v.f = f;
  unsigned int u = v.u;
  u += 0x7fffu + ((u >> 16) & 1u);   // RNE
  return (unsigned short)(u >> 16);
}

// native RNE cast — compiler emits v_cvt_pk_bf16_f32 for pairs (hot paths)
__device__ __forceinline__ unsigned short f2bf_hw(float f) {
  return __builtin_bit_cast(unsigned short, (__bf16)f);
}

// pack two f32 -> u32 of 2 bf16 (compiler fuses to v_cvt_pk_bf16_f32)
__device__ __forceinline__ unsigned int pk2bf(float lo, float hi) {
  return (unsigned int)f2bf_hw(lo) | ((unsigned int)f2bf_hw(hi) << 16);
}

// ---------------- fused prep: cvt_x + transpose(qkv_w) + transpose(proj_w) ----
__global__ __launch_bounds__(256) void prep_kernel(
    const float* __restrict__ x, unsigned short* __restrict__ x_bf,
    const float* __restrict__ qkv_w, unsigned short* __restrict__ qkvw_t,
    const float* __restrict__ proj_w, unsigned short* __restrict__ projw_t)
{
  __shared__ float tile[32][33];
  const int bid = blockIdx.x, tid = threadIdx.x;
  if (bid < 8192) {                       // x: fp32 -> bf16, 4 elems/thread
    const int i = bid * 256 + tid;
    float4 v = ((const float4*)x)[i];
    ushort4 o;
    o.x = f2bf(v.x); o.y = f2bf(v.y); o.z = f2bf(v.z); o.w = f2bf(v.w);
    ((ushort4*)x_bf)[i] = o;
    return;
  }
  const float* W; unsigned short* Wt; int N, bx, by;
  if (bid < 14336) { const int v = bid - 8192;  W = qkv_w;  Wt = qkvw_t;  N = QKV_N;   bx = v % 96; by = v / 96; }
  else             { const int v = bid - 14336; W = proj_w; Wt = projw_t; N = D_MODEL; bx = v % 64; by = v / 64; }
  const int K = D_MODEL;
  const int n0 = bx * 32, k0 = by * 32;
  const int tx = tid & 31, ty = tid >> 5;   // (32, 8)
  #pragma unroll
  for (int i = 0; i < 32; i += 8)
    tile[ty + i][tx] = W[(size_t)(k0 + ty + i) * N + n0 + tx];
  __syncthreads();
  #pragma unroll
  for (int i = 0; i < 32; i += 8)
    Wt[(size_t)(n0 + ty + i) * K + k0 + tx] = f2bf(tile[tx][ty + i]);
}

// ------- 256-row x (NB*128)-col 8-phase bf16 GEMM: C = A * Bt^T + bias ---------
// NB=2: BN=256, LDS 128K, vmcnt(6). NB=1: BN=128, LDS 96K, vmcnt(4).
// SWZ=1: T1 XCD swizzle (proven -40us on GEMM1: FETCH 78->57.6MB, MfmaUtil
// 17->25.5). SWZ=0: natural mapping — for GEMM2 the default round-robin gives
// each XCD a 1MB L2-resident B panel already (R9 measured: swizzle HURT it).
// cmode 0: C = f32[M][N]. cmode 2: fused QKV epilogue (Q compact / kst / vst
// with sigma key-permutation for attn's lane-local PV).
template<int NB, int SWZ>
__global__ __launch_bounds__(512, 2) void gemm256(
    const unsigned short* __restrict__ A,
    const unsigned short* __restrict__ Bt,
    const float* __restrict__ bias,
    void* __restrict__ Cout,
    unsigned short* __restrict__ kst,
    unsigned short* __restrict__ vst,
    int M, int N, int K, int cmode)
{
  __shared__ __align__(16) unsigned short lds[32768 + NB * 16384];
  const int tid  = threadIdx.x;
  const int wave = tid >> 6, lane = tid & 63;
  const int quad = lane >> 4, l16 = lane & 15;
  const int wr = wave >> 2, wc = wave & 3;        // 2 x 4 wave grid

  int bm, bn;
  if (SWZ) {
    // T1 bijective XCD swizzle (nwg % 8 == 0)
    const int nwg = gridDim.x * gridDim.y;
    const int cpx = nwg >> 3;
    const int f   = blockIdx.y * gridDim.x + blockIdx.x;
    const int w   = (f & 7) * cpx + (f >> 3);
    bm = (w / gridDim.x) * 256;
    bn = (w % gridDim.x) * (NB * 128);
  } else {
    bm = blockIdx.y * 256;
    bn = blockIdx.x * (NB * 128);
  }
  const int NT = K >> 6;                          // 64-wide K tiles

  const int r0 = tid >> 3;                        // row 0..63 (j=0)
  const int cx = (tid & 7) ^ (r0 & 7);            // inverse swizzle of k-chunk
  const size_t K64 = (size_t)64 * K;              // 64 rows worth of elements
  const unsigned short* a_src = A  + (size_t)(bm + r0) * K + cx * 8;
  const unsigned short* b_src = Bt + (size_t)(bn + r0) * K + cx * 8;
  const int wOff = wave * 512;                    // wave-uniform LDS offset (elems)

  #define LDSA_(buf, half) (lds + (((buf) << 1) + (half)) * 8192)
  #define LDSB_(buf, half) (lds + 32768 + (((buf) << 1) + (half)) * (NB * 4096))
  #define KOFFA(h, t) ((size_t)(h) * 128 * K + (size_t)(t) * 64)
  #define KOFFB(h, t) ((size_t)(h) * (64 * NB) * K + (size_t)(t) * 64)
  #define STAGE_A(srcbase, ldshalf, koff) do {                                        \
    __builtin_amdgcn_global_load_lds((gvoid_t*)((srcbase) + (koff)),                  \
        (svoid_t*)((ldshalf) + wOff), 16, 0, 0);                                      \
    __builtin_amdgcn_global_load_lds((gvoid_t*)((srcbase) + (koff) + K64),            \
        (svoid_t*)((ldshalf) + wOff + 4096), 16, 0, 0);                               \
  } while (0)
  #define STAGE_B(srcbase, ldshalf, koff) do {                                        \
    _Pragma("unroll")                                                                 \
    for (int j_ = 0; j_ < NB; ++j_)                                                   \
      __builtin_amdgcn_global_load_lds(                                               \
          (gvoid_t*)((srcbase) + (koff) + (size_t)j_ * K64),                          \
          (svoid_t*)((ldshalf) + wOff + j_ * 4096), 16, 0, 0);                        \
  } while (0)

  const int rowA = (wr * 64 + l16) * 64;          // within half-tile, elems
  const int rowB = (wc * (16 * NB) + l16) * 64;
  const int xo0 = ((quad)     ^ (l16 & 7)) * 8;   // ks=0 chunk
  const int xo1 = ((4 + quad) ^ (l16 & 7)) * 8;   // ks=1 chunk

  floatx4 acc[8][2 * NB] = {};
  shortx8 Afr[4][2];
  shortx8 Bfr[2 * NB][2];

  STAGE_A(a_src, LDSA_(0, 0), KOFFA(0, 0));
  STAGE_B(b_src, LDSB_(0, 0), KOFFB(0, 0));
  STAGE_B(b_src, LDSB_(0, 1), KOFFB(1, 0));
  STAGE_A(a_src, LDSA_(0, 1), KOFFA(1, 0));
  if (NT > 1) {
    STAGE_A(a_src, LDSA_(1, 0), KOFFA(0, 1));
    STAGE_B(b_src, LDSB_(1, 0), KOFFB(0, 1));
    STAGE_B(b_src, LDSB_(1, 1), KOFFB(1, 1));
  }

  for (int t = 0; t < NT; ++t) {
    const int buf = t & 1;
    unsigned short* sA0 = LDSA_(buf, 0);
    unsigned short* sA1 = LDSA_(buf, 1);
    unsigned short* sB0 = LDSB_(buf, 0);
    unsigned short* sB1 = LDSB_(buf, 1);

    // ---- phase 0 ----
    if (t == NT - 1) asm volatile("s_waitcnt vmcnt(0)" ::: "memory");
    else if constexpr (NB == 2) asm volatile("s_waitcnt vmcnt(6)" ::: "memory");
    else                        asm volatile("s_waitcnt vmcnt(4)" ::: "memory");
    __builtin_amdgcn_s_barrier();
    #pragma unroll
    for (int mi = 0; mi < 4; ++mi) {
      Afr[mi][0] = *(const shortx8*)(sA0 + rowA + mi * 1024 + xo0);
      Afr[mi][1] = *(const shortx8*)(sA0 + rowA + mi * 1024 + xo1);
    }
    #pragma unroll
    for (int ni = 0; ni < NB; ++ni) {
      Bfr[ni][0] = *(const shortx8*)(sB0 + rowB + ni * 1024 + xo0);
      Bfr[ni][1] = *(const shortx8*)(sB0 + rowB + ni * 1024 + xo1);
    }
    if (t + 1 < NT) STAGE_A(a_src, LDSA_(buf ^ 1, 1), KOFFA(1, t + 1));
    asm volatile("s_waitcnt lgkmcnt(0)" ::: "memory");
    __builtin_amdgcn_s_setprio(1);
    #pragma unroll
    for (int ks = 0; ks < 2; ++ks)
      #pragma unroll
      for (int mi = 0; mi < 4; ++mi)
        #pragma unroll
        for (int ni = 0; ni < NB; ++ni)
          acc[mi][ni] = mfma16(Afr[mi][ks], Bfr[ni][ks], acc[mi][ni]);
    __builtin_amdgcn_s_setprio(0);
    __builtin_amdgcn_s_barrier();

    // ---- phase 1 ----
    #pragma unroll
    for (int ni = 0; ni < NB; ++ni) {
      Bfr[NB + ni][0] = *(const shortx8*)(sB1 + rowB + ni * 1024 + xo0);
      Bfr[NB + ni][1] = *(const shortx8*)(sB1 + rowB + ni * 1024 + xo1);
    }
    if (t + 2 < NT) STAGE_A(a_src, LDSA_(buf, 0), KOFFA(0, t + 2));
    __builtin_amdgcn_s_barrier();
    asm volatile("s_waitcnt lgkmcnt(0)" ::: "memory");
    __builtin_amdgcn_s_setprio(1);
    #pragma unroll
    for (int ks = 0; ks < 2; ++ks)
      #pragma unroll
      for (int mi = 0; mi < 4; ++mi)
        #pragma unroll
        for (int ni = 0; ni < NB; ++ni)
          acc[mi][NB + ni] = mfma16(Afr[mi][ks], Bfr[NB + ni][ks], acc[mi][NB + ni]);
    __builtin_amdgcn_s_setprio(0);
    __builtin_amdgcn_s_barrier();

    // ---- phase 2 ----
    #pragma unroll
    for (int mi = 0; mi < 4; ++mi) {
      Afr[mi][0] = *(const shortx8*)(sA1 + rowA + mi * 1024 + xo0);
      Afr[mi][1] = *(const shortx8*)(sA1 + rowA + mi * 1024 + xo1);
    }
    if (t + 2 < NT) STAGE_B(b_src, LDSB_(buf, 0), KOFFB(0, t + 2));
    __builtin_amdgcn_s_barrier();
    asm volatile("s_waitcnt lgkmcnt(0)" ::: "memory");
    __builtin_amdgcn_s_setprio(1);
    #pragma unroll
    for (int ks = 0; ks < 2; ++ks)
      #pragma unroll
      for (int mi = 0; mi < 4; ++mi)
        #pragma unroll
        for (int ni = 0; ni < NB; ++ni)
          acc[4 + mi][NB + ni] = mfma16(Afr[mi][ks], Bfr[NB + ni][ks], acc[4 + mi][NB + ni]);
    __builtin_amdgcn_s_setprio(0);
    __builtin_amdgcn_s_barrier();

    // ---- phase 3 ----
    if (t + 2 < NT) STAGE_B(b_src, LDSB_(buf, 1), KOFFB(1, t + 2));
    __builtin_amdgcn_s_barrier();
    __builtin_amdgcn_s_setprio(1);
    #pragma unroll
    for (int ks = 0; ks < 2; ++ks)
      #pragma unroll
      for (int mi = 0; mi < 4; ++mi)
        #pragma unroll
        for (int ni = 0; ni < NB; ++ni)
          acc[4 + mi][ni] = mfma16(Afr[mi][ks], Bfr[ni][ks], acc[4 + mi][ni]);
    __builtin_amdgcn_s_setprio(0);
    __builtin_amdgcn_s_barrier();
  }

  #pragma unroll
  for (int mi = 0; mi < 8; ++mi) {
    const int row = bm + (mi >> 2) * 128 + wr * 64 + (mi & 3) * 16 + quad * 4;
    #pragma unroll
    for (int ni = 0; ni < 2 * NB; ++ni) {
      const int col = bn + (ni / NB) * (64 * NB) + wc * (16 * NB) + (ni % NB) * 16 + l16;
      const float bv = bias[col];
      #pragma unroll
      for (int r = 0; r < 4; ++r) {
        float v = acc[mi][ni][r] + bv;
        if (cmode == 0) {
          ((float*)Cout)[(size_t)(row + r) * N + col] = v;
        } else {
          const unsigned short h = f2bf_hw(v);
          const int rw = row + r;
          const int t = rw & 2047, bb = rw >> 11;
          if (col < 2048) {
            ((unsigned short*)Cout)[(size_t)rw * 2048 + col] = h;
          } else if (col < 2560) {
            // K staged: [b][kvh][d8][t][8]
            const int c2 = col - 2048, kvh = c2 >> 7, d = c2 & 127;
            kst[((((size_t)bb * 4 + kvh) * 16 + (d >> 3)) * 2048 + t) * 8 + (d & 7)] = h;
          } else {
            // V staged: [b][kvh][t8'][d][8] with sigma key-permutation:
            // slot ts = (t&~31) | ((t>>2)&3)<<3 | ((t>>4)&1)<<2 | (t&3)
            const int c2 = col - 2560, kvh = c2 >> 7, d = c2 & 127;
            const int ts = (t & ~31) | (((t >> 2) & 3) << 3) | (((t >> 4) & 1) << 2) | (t & 3);
            vst[((((size_t)bb * 4 + kvh) * 256 + (ts >> 3)) * 128 + d) * 8 + (ts & 7)] = h;
          }
        }
      }
    }
  }
  #undef LDSA_
  #undef LDSB_
  #undef KOFFA
  #undef KOFFB
  #undef STAGE_A
  #undef STAGE_B
}

// ---------------- flash attention, GQA, causal — swapped-QK in-register softmax
// R8 mapping restored (R9's XCD swizzle cost ~20-40us here — reverted).
// grid (16, N_HEADS, B) = 512 blocks x 512 threads; wave = (split, rowgroup).
// st = mfma(K,Q); scalar m/l per lane, P packed in-register, PV via
// sigma-permuted V. LDS 64 KB -> 2 blocks/CU = 4 waves/SIMD.
__global__ __launch_bounds__(512, 4) void attn_kernel(
    const unsigned short* __restrict__ qbuf,  // (B*T, 2048) bf16 Q
    const unsigned short* __restrict__ kst,   // [b][kvh][d8][t][8]
    const unsigned short* __restrict__ vst,   // [b][kvh][t8'][d][8] (sigma-permuted)
    unsigned short* __restrict__ aout)        // (B*T, D_MODEL) bf16
{
  __shared__ __align__(16) unsigned short sK[2][16 * 64 * 8];   // per split [d8][key][8]
  __shared__ __align__(16) unsigned short sV[2][8 * 128 * 8];   // per split [t8'][d][8]

  const int tid  = threadIdx.x;
  const int wave = tid >> 6, lane = tid & 63;
  const int split = wave >> 2, g = wave & 3;
  const int quad = lane >> 4, l16 = lane & 15;
  const int head = blockIdx.y, b = blockIdx.z;
  const int kvh = head >> 2;
  const float cf = 0.08838834764831845f * 1.4426950408889634f;  // scale*log2e
  const float THR = 25.0f;  // defer-max threshold (raw S units)

  const unsigned short* kbase = kst + (size_t)((b * KV_HEADS + kvh) * 16) * 2048 * 8;
  const unsigned short* vbase = vst + (size_t)((b * KV_HEADS + kvh) * 256) * 128 * 8;

  // merge scratch overlays K/V LDS (used only after the kt loop, post-barrier)
  float* mrgO  = (float*)&sK[0][0];   // [g][d=128][q=16] f32 = 32 KB
  float* mrgML = (float*)&sV[0][0];   // [g][lane][{m,l}] f32 = 2 KB

  #define STAGE_KV(sp, kb_) do {                                               \
    _Pragma("unroll")                                                          \
    for (int it_ = 0; it_ < 4; ++it_) {                                        \
      const int c_ = it_ * 4 + g;                                              \
      __builtin_amdgcn_global_load_lds(                                        \
          (gvoid_t*)(kbase + ((size_t)c_ * 2048 + (kb_)) * 8 + lane * 8),      \
          (svoid_t*)(&sK[sp][c_ * 512]), 16, 0, 0);                            \
    }                                                                          \
    const unsigned short* vt_ = vbase + (size_t)((kb_) >> 3) * 128 * 8;        \
    _Pragma("unroll")                                                          \
    for (int it_ = 0; it_ < 4; ++it_) {                                        \
      const int c_ = it_ * 4 + g;                                              \
      __builtin_amdgcn_global_load_lds(                                        \
          (gvoid_t*)(vt_ + c_ * 512 + lane * 8),                               \
          (svoid_t*)(&sV[sp][c_ * 512]), 16, 0, 0);                            \
    }                                                                          \
  } while (0)

  #pragma unroll 1
  for (int half = 0; half < 2; ++half) {
    const int qt = half ? blockIdx.x : (31 - blockIdx.x);
    const int q0 = qt * 64;

    // Q fragments (query = q0 + g*16 + l16; B-operand role)
    shortx8 qf[4];
    {
      const unsigned short* qp = qbuf + (size_t)(b * T_SEQ + q0 + g * 16 + l16) * 2048
                                 + head * HEAD_DIM + quad * 8;
      #pragma unroll
      for (int ks = 0; ks < 4; ++ks)
        qf[ks] = *(const shortx8*)(qp + ks * 32);
    }

    float m_i = -__builtin_inff(), l_i = 0.f;
    floatx4 o_acc[8] = {};   // [nt]: O[query=l16][d = nt*16 + quad*4 + r]

    const int J = (qt >> 1) + 1;   // ceil((qt+1)/2)
    for (int j = 0; j < J; ++j) {
      const int kt = 2 * j + split;
      const bool act = (kt <= qt);
      floatx4 st[4] = {};          // st[ct][r] = S[query=l16][key=kt*64+ct*16+quad*4+r]
      unsigned int pk[4][2];       // packed bf16 P, 2 u32 per ct

      __builtin_amdgcn_s_barrier();   // A: prev iteration's LDS reads complete
      if (act) STAGE_KV(split, kt * 64);
      asm volatile("s_waitcnt vmcnt(4)" ::: "memory");  // K written; V in flight
      __builtin_amdgcn_s_barrier();   // B: K tile visible to the split's waves

      if (act) {
        // S^T = K Q^T (swapped operands; same fragments)
        __builtin_amdgcn_s_setprio(1);
        #pragma unroll
        for (int ks = 0; ks < 4; ++ks) {
          #pragma unroll
          for (int ct = 0; ct < 4; ++ct) {
            shortx8 kf = *(const shortx8*)&sK[split][((ks * 4 + quad) * 64 + ct * 16 + l16) * 8];
            st[ct] = mfma16(kf, qf[ks], st[ct]);
          }
        }
        __builtin_amdgcn_s_setprio(0);

        // causal mask on the diagonal tile
        if (kt == qt) {
          const int qrow = q0 + g * 16 + l16;
          const int kb = kt * 64;
          #pragma unroll
          for (int ct = 0; ct < 4; ++ct) {
            #pragma unroll
            for (int r = 0; r < 4; ++r)
              if (kb + ct * 16 + quad * 4 + r > qrow) st[ct][r] = -__builtin_inff();
          }
        }

        // local 16-max; defer-max: full 2-shuffle reduce only when triggered
        float lmx = -__builtin_inff();
        #pragma unroll
        for (int ct = 0; ct < 4; ++ct)
          lmx = fmaxf(lmx, fmaxf(fmaxf(st[ct][0], st[ct][1]), fmaxf(st[ct][2], st[ct][3])));
        if (__ballot(lmx > m_i + THR)) {
          float m = lmx;
          m = fmaxf(m, __shfl_xor(m, 16));
          m = fmaxf(m, __shfl_xor(m, 32));
          const float newm = fmaxf(m_i, m);
          const float alpha = exp2f((m_i - newm) * cf);
          m_i = newm;
          l_i *= alpha;
          #pragma unroll
          for (int nt = 0; nt < 8; ++nt)
            #pragma unroll
            for (int r = 0; r < 4; ++r) o_acc[nt][r] *= alpha;
        }

        // P = exp2((S - m)*cf); accumulate partial l; pack to bf16 in-register
        const float nmc = m_i * cf;
        float ps = 0.f;
        #pragma unroll
        for (int ct = 0; ct < 4; ++ct) {
          #pragma unroll
          for (int r = 0; r < 4; ++r) {
            st[ct][r] = exp2f(fmaf(st[ct][r], cf, -nmc));
            ps += st[ct][r];
          }
          pk[ct][0] = pk2bf(st[ct][0], st[ct][1]);
          pk[ct][1] = pk2bf(st[ct][2], st[ct][3]);
        }
        l_i += ps;
      }

      asm volatile("s_waitcnt vmcnt(0)" ::: "memory");  // own V writes done
      __builtin_amdgcn_s_barrier();   // C: V tile visible

      if (act) {
        // O^T += V^T P^T : A = vf (d rows), B = pa (lane-local packed P)
        #pragma unroll
        for (int kc = 0; kc < 2; ++kc) {
          union { unsigned int u[4]; shortx8 s; } pa;
          pa.u[0] = pk[2 * kc][0];     pa.u[1] = pk[2 * kc][1];
          pa.u[2] = pk[2 * kc + 1][0]; pa.u[3] = pk[2 * kc + 1][1];
          __builtin_amdgcn_s_setprio(1);
          #pragma unroll
          for (int nt = 0; nt < 8; ++nt) {
            shortx8 vf = *(const shortx8*)&sV[split][((kc * 4 + quad) * 128 + nt * 16 + l16) * 8];
            o_acc[nt] = mfma16(vf, pa.s, o_acc[nt]);
          }
          __builtin_amdgcn_s_setprio(0);
        }
      }
    }

    // ---- merge split partials, then epilogue (split0 finalizes) ----
    __builtin_amdgcn_s_barrier();   // all compute reads of K/V LDS done
    if (split == 1) {
      #pragma unroll
      for (int nt = 0; nt < 8; ++nt)
        #pragma unroll
        for (int r = 0; r < 4; ++r)
          mrgO[g * 2048 + (nt * 16 + quad * 4 + r) * 16 + l16] = o_acc[nt][r];
      mrgML[(g * 64 + lane) * 2]     = m_i;
      mrgML[(g * 64 + lane) * 2 + 1] = l_i;
    }
    asm volatile("s_waitcnt lgkmcnt(0)" ::: "memory");
    __builtin_amdgcn_s_barrier();   // partials visible

    if (split == 0) {
      const float m1 = mrgML[(g * 64 + lane) * 2];
      const float l1 = mrgML[(g * 64 + lane) * 2 + 1];
      const float M  = fmaxf(m_i, m1);
      const float a0 = exp2f((m_i - M) * cf);
      const float a1 = exp2f((m1 - M) * cf);
      float lm = a0 * l_i + a1 * l1;
      #pragma unroll
      for (int nt = 0; nt < 8; ++nt)
        #pragma unroll
        for (int r = 0; r < 4; ++r)
          o_acc[nt][r] = a0 * o_acc[nt][r]
                       + a1 * mrgO[g * 2048 + (nt * 16 + quad * 4 + r) * 16 + l16];

      lm += __shfl_xor(lm, 16);
      lm += __shfl_xor(lm, 32);
      const float inv = 1.f / lm;
      const size_t orow = (size_t)(b * T_SEQ + q0 + g * 16 + l16) * D_MODEL + head * HEAD_DIM;
      #pragma unroll
      for (int nt = 0; nt < 8; ++nt) {
        uint2 w2;
        w2.x = pk2bf(o_acc[nt][0] * inv, o_acc[nt][1] * inv);
        w2.y = pk2bf(o_acc[nt][2] * inv, o_acc[nt][3] * inv);
        *(uint2*)&aout[orow + nt * 16 + quad * 4] = w2;
      }
    }
  }
  #undef STAGE_KV
}

extern "C" void kernel_launch(void* const* d_in, const int* in_sizes, int n_in,
                              void* d_out, int out_size, void* d_ws, size_t ws_size,
                              hipStream_t stream) {
  const float* x      = (const float*)d_in[0];
  // d_in[1] = attn_mask (causal; unused)
  const float* qkv_w  = (const float*)d_in[2];
  const float* qkv_b  = (const float*)d_in[3];
  const float* proj_w = (const float*)d_in[4];
  const float* proj_b = (const float*)d_in[5];
  float* out = (float*)d_out;

  char* ws = (char*)d_ws;
  // workspace map (bytes):
  //   [0,16M)            x_bf (GEMM1 A), later attn_out
  //   [16M, 29.36M)      qkvw_t
  //   [29.36M, 37.75M)   projw_t
  //   [37.75M, 54.53M)   qbuf
  //   [54.53M, 58.72M)   kstaged
  //   [58.72M, 62.91M)   vstaged (sigma-permuted)
  unsigned short* x_bf    = (unsigned short*)(ws);
  unsigned short* qkvw_t  = (unsigned short*)(ws + (size_t)16777216);
  unsigned short* projw_t = (unsigned short*)(ws + (size_t)29360128);
  unsigned short* qbuf    = (unsigned short*)(ws + (size_t)37748736);
  unsigned short* kstaged = (unsigned short*)(ws + (size_t)54525952);
  unsigned short* vstaged = (unsigned short*)(ws + (size_t)58720256);
  unsigned short* attn_out = x_bf;   // safe alias: x_bf dead after GEMM1

  prep_kernel<<<18432, 256, 0, stream>>>(x, x_bf, qkv_w, qkvw_t, proj_w, projw_t);
  gemm256<2, 1><<<dim3(QKV_N / 256, ROWS / 256), 512, 0, stream>>>(
      x_bf, qkvw_t, qkv_b, (void*)qbuf, kstaged, vstaged, ROWS, QKV_N, D_MODEL, 2);
  attn_kernel<<<dim3(16, N_HEADS, BATCH), 512, 0, stream>>>(qbuf, kstaged, vstaged, attn_out);
  gemm256<1, 0><<<dim3(D_MODEL / 128, ROWS / 256), 512, 0, stream>>>(
      attn_out, projw_t, proj_b, (void*)out, nullptr, nullptr, ROWS, D_MODEL, D_MODEL, 0);
}

// Round 11
// 289.115 us; speedup vs baseline: 1.0199x; 1.0176x over previous
//
#include <hip/hip_runtime.h>
#include <cstdint>
#include <cstddef>

#define D_MODEL 2048
#define T_SEQ   2048
#define BATCH   2
#define N_HEADS 16
#define KV_HEADS 4
#define HEAD_DIM 128
#define QKV_N   3072          // D_MODEL + 2*512
#define ROWS    (BATCH * T_SEQ) // 4096

typedef float  floatx4 __attribute__((ext_vector_type(4)));
typedef short  shortx8 __attribute__((ext_vector_type(8)));
typedef __bf16 bf16x8  __attribute__((ext_vector_type(8)));

typedef const void __attribute__((address_space(1))) gvoid_t;
typedef void __attribute__((address_space(3)))       svoid_t;

__device__ __forceinline__ floatx4 mfma16(shortx8 a, shortx8 b, floatx4 c) {
  return __builtin_amdgcn_mfma_f32_16x16x32_bf16(
      __builtin_bit_cast(bf16x8, a), __builtin_bit_cast(bf16x8, b), c, 0, 0, 0);
}

__device__ __forceinline__ unsigned short f2bf(float f) {
  union { float f; unsigned int u; } v; v.f = f;
  unsigned int u = v.u;
  u += 0x7fffu + ((u >> 16) & 1u);   // RNE
  return (unsigned short)(u >> 16);
}

// native RNE cast — compiler emits v_cvt_pk_bf16_f32 for pairs (hot paths)
__device__ __forceinline__ unsigned short f2bf_hw(float f) {
  return __builtin_bit_cast(unsigned short, (__bf16)f);
}

// pack two f32 -> u32 of 2 bf16 (compiler fuses to v_cvt_pk_bf16_f32)
__device__ __forceinline__ unsigned int pk2bf(float lo, float hi) {
  return (unsigned int)f2bf_hw(lo) | ((unsigned int)f2bf_hw(hi) << 16);
}

// ---------------- fused prep: cvt_x + transpose(qkv_w) + transpose(proj_w) ----
__global__ __launch_bounds__(256) void prep_kernel(
    const float* __restrict__ x, unsigned short* __restrict__ x_bf,
    const float* __restrict__ qkv_w, unsigned short* __restrict__ qkvw_t,
    const float* __restrict__ proj_w, unsigned short* __restrict__ projw_t)
{
  __shared__ float tile[32][33];
  const int bid = blockIdx.x, tid = threadIdx.x;
  if (bid < 8192) {                       // x: fp32 -> bf16, 4 elems/thread
    const int i = bid * 256 + tid;
    float4 v = ((const float4*)x)[i];
    ushort4 o;
    o.x = f2bf(v.x); o.y = f2bf(v.y); o.z = f2bf(v.z); o.w = f2bf(v.w);
    ((ushort4*)x_bf)[i] = o;
    return;
  }
  const float* W; unsigned short* Wt; int N, bx, by;
  if (bid < 14336) { const int v = bid - 8192;  W = qkv_w;  Wt = qkvw_t;  N = QKV_N;   bx = v % 96; by = v / 96; }
  else             { const int v = bid - 14336; W = proj_w; Wt = projw_t; N = D_MODEL; bx = v % 64; by = v / 64; }
  const int K = D_MODEL;
  const int n0 = bx * 32, k0 = by * 32;
  const int tx = tid & 31, ty = tid >> 5;   // (32, 8)
  #pragma unroll
  for (int i = 0; i < 32; i += 8)
    tile[ty + i][tx] = W[(size_t)(k0 + ty + i) * N + n0 + tx];
  __syncthreads();
  #pragma unroll
  for (int i = 0; i < 32; i += 8)
    Wt[(size_t)(n0 + ty + i) * K + k0 + tx] = f2bf(tile[tx][ty + i]);
}

// ------- 256-row x (NB*128)-col barrier-minimal bf16 GEMM ----------------------
// One s_barrier + one (steady-state-free) vmcnt(0) per K-tile: ALL staging for
// tile t+1 targets the OTHER LDS buffer (depth-1 prefetch), so the 4 MFMA
// quadrants run barrier-free with compiler-counted lgkmcnt overlapping
// ds_reads and MFMAs across quadrants. (Prev: 8 barriers + 4 drains/tile.)
// SWZ=1: T1 XCD swizzle (G1). cmode 0: C=f32. cmode 2: fused QKV epilogue.
template<int NB, int SWZ>
__global__ __launch_bounds__(512, 2) void gemm256(
    const unsigned short* __restrict__ A,
    const unsigned short* __restrict__ Bt,
    const float* __restrict__ bias,
    void* __restrict__ Cout,
    unsigned short* __restrict__ kst,
    unsigned short* __restrict__ vst,
    int M, int N, int K, int cmode)
{
  __shared__ __align__(16) unsigned short lds[32768 + NB * 16384];
  const int tid  = threadIdx.x;
  const int wave = tid >> 6, lane = tid & 63;
  const int quad = lane >> 4, l16 = lane & 15;
  const int wr = wave >> 2, wc = wave & 3;        // 2 x 4 wave grid

  int bm, bn;
  if (SWZ) {
    // T1 bijective XCD swizzle (nwg % 8 == 0)
    const int nwg = gridDim.x * gridDim.y;
    const int cpx = nwg >> 3;
    const int f   = blockIdx.y * gridDim.x + blockIdx.x;
    const int w   = (f & 7) * cpx + (f >> 3);
    bm = (w / gridDim.x) * 256;
    bn = (w % gridDim.x) * (NB * 128);
  } else {
    bm = blockIdx.y * 256;
    bn = blockIdx.x * (NB * 128);
  }
  const int NT = K >> 6;                          // 64-wide K tiles

  const int r0 = tid >> 3;                        // row 0..63 (j=0)
  const int cx = (tid & 7) ^ (r0 & 7);            // inverse swizzle of k-chunk
  const size_t K64 = (size_t)64 * K;              // 64 rows worth of elements
  const unsigned short* a_src = A  + (size_t)(bm + r0) * K + cx * 8;
  const unsigned short* b_src = Bt + (size_t)(bn + r0) * K + cx * 8;
  const int wOff = wave * 512;                    // wave-uniform LDS offset (elems)

  #define LDSA_(buf, half) (lds + (((buf) << 1) + (half)) * 8192)
  #define LDSB_(buf, half) (lds + 32768 + (((buf) << 1) + (half)) * (NB * 4096))
  #define KOFFA(h, t) ((size_t)(h) * 128 * K + (size_t)(t) * 64)
  #define KOFFB(h, t) ((size_t)(h) * (64 * NB) * K + (size_t)(t) * 64)
  #define STAGE_A(srcbase, ldshalf, koff) do {                                        \
    __builtin_amdgcn_global_load_lds((gvoid_t*)((srcbase) + (koff)),                  \
        (svoid_t*)((ldshalf) + wOff), 16, 0, 0);                                      \
    __builtin_amdgcn_global_load_lds((gvoid_t*)((srcbase) + (koff) + K64),            \
        (svoid_t*)((ldshalf) + wOff + 4096), 16, 0, 0);                               \
  } while (0)
  #define STAGE_B(srcbase, ldshalf, koff) do {                                        \
    _Pragma("unroll")                                                                 \
    for (int j_ = 0; j_ < NB; ++j_)                                                   \
      __builtin_amdgcn_global_load_lds(                                               \
          (gvoid_t*)((srcbase) + (koff) + (size_t)j_ * K64),                          \
          (svoid_t*)((ldshalf) + wOff + j_ * 4096), 16, 0, 0);                        \
  } while (0)
  // stage one FULL K-tile (A both halves + B both halves) into buffer bf_
  #define STAGE_TILE(bf_, tt_) do {                                                   \
    STAGE_A(a_src, LDSA_(bf_, 0), KOFFA(0, tt_));                                     \
    STAGE_A(a_src, LDSA_(bf_, 1), KOFFA(1, tt_));                                     \
    STAGE_B(b_src, LDSB_(bf_, 0), KOFFB(0, tt_));                                     \
    STAGE_B(b_src, LDSB_(bf_, 1), KOFFB(1, tt_));                                     \
  } while (0)

  const int rowA = (wr * 64 + l16) * 64;          // within half-tile, elems
  const int rowB = (wc * (16 * NB) + l16) * 64;
  const int xo0 = ((quad)     ^ (l16 & 7)) * 8;   // ks=0 chunk
  const int xo1 = ((4 + quad) ^ (l16 & 7)) * 8;   // ks=1 chunk

  floatx4 acc[8][2 * NB] = {};
  shortx8 Afr[4][2];
  shortx8 Bfr[2 * NB][2];

  // prologue: stage tile 0 into buffer 0
  STAGE_TILE(0, 0);

  for (int t = 0; t < NT; ++t) {
    const int buf = t & 1;
    unsigned short* sA0 = LDSA_(buf, 0);
    unsigned short* sA1 = LDSA_(buf, 1);
    unsigned short* sB0 = LDSB_(buf, 0);
    unsigned short* sB1 = LDSB_(buf, 1);

    // own tile-t loads done (issued a full tile ago in steady state -> ~free)
    asm volatile("s_waitcnt vmcnt(0)" ::: "memory");
    // all waves' tile-t loads landed; all waves done reading buffer buf^1
    __builtin_amdgcn_s_barrier();
    // prefetch tile t+1 into the other buffer (no intra-tile hazards left)
    if (t + 1 < NT) STAGE_TILE(buf ^ 1, t + 1);

    // ---- quadrant 0: A-half0 x B-half0 ----
    #pragma unroll
    for (int mi = 0; mi < 4; ++mi) {
      Afr[mi][0] = *(const shortx8*)(sA0 + rowA + mi * 1024 + xo0);
      Afr[mi][1] = *(const shortx8*)(sA0 + rowA + mi * 1024 + xo1);
    }
    #pragma unroll
    for (int ni = 0; ni < NB; ++ni) {
      Bfr[ni][0] = *(const shortx8*)(sB0 + rowB + ni * 1024 + xo0);
      Bfr[ni][1] = *(const shortx8*)(sB0 + rowB + ni * 1024 + xo1);
    }
    __builtin_amdgcn_s_setprio(1);
    #pragma unroll
    for (int ks = 0; ks < 2; ++ks)
      #pragma unroll
      for (int mi = 0; mi < 4; ++mi)
        #pragma unroll
        for (int ni = 0; ni < NB; ++ni)
          acc[mi][ni] = mfma16(Afr[mi][ks], Bfr[ni][ks], acc[mi][ni]);
    __builtin_amdgcn_s_setprio(0);

    // ---- quadrant 1: A-half0 x B-half1 ----
    #pragma unroll
    for (int ni = 0; ni < NB; ++ni) {
      Bfr[NB + ni][0] = *(const shortx8*)(sB1 + rowB + ni * 1024 + xo0);
      Bfr[NB + ni][1] = *(const shortx8*)(sB1 + rowB + ni * 1024 + xo1);
    }
    __builtin_amdgcn_s_setprio(1);
    #pragma unroll
    for (int ks = 0; ks < 2; ++ks)
      #pragma unroll
      for (int mi = 0; mi < 4; ++mi)
        #pragma unroll
        for (int ni = 0; ni < NB; ++ni)
          acc[mi][NB + ni] = mfma16(Afr[mi][ks], Bfr[NB + ni][ks], acc[mi][NB + ni]);
    __builtin_amdgcn_s_setprio(0);

    // ---- quadrant 2: A-half1 x B-half1 ----
    #pragma unroll
    for (int mi = 0; mi < 4; ++mi) {
      Afr[mi][0] = *(const shortx8*)(sA1 + rowA + mi * 1024 + xo0);
      Afr[mi][1] = *(const shortx8*)(sA1 + rowA + mi * 1024 + xo1);
    }
    __builtin_amdgcn_s_setprio(1);
    #pragma unroll
    for (int ks = 0; ks < 2; ++ks)
      #pragma unroll
      for (int mi = 0; mi < 4; ++mi)
        #pragma unroll
        for (int ni = 0; ni < NB; ++ni)
          acc[4 + mi][NB + ni] = mfma16(Afr[mi][ks], Bfr[NB + ni][ks], acc[4 + mi][NB + ni]);
    __builtin_amdgcn_s_setprio(0);

    // ---- quadrant 3: A-half1 x B-half0 (Bfr[0..NB) still live) ----
    __builtin_amdgcn_s_setprio(1);
    #pragma unroll
    for (int ks = 0; ks < 2; ++ks)
      #pragma unroll
      for (int mi = 0; mi < 4; ++mi)
        #pragma unroll
        for (int ni = 0; ni < NB; ++ni)
          acc[4 + mi][ni] = mfma16(Afr[mi][ks], Bfr[ni][ks], acc[4 + mi][ni]);
    __builtin_amdgcn_s_setprio(0);
  }

  #pragma unroll
  for (int mi = 0; mi < 8; ++mi) {
    const int row = bm + (mi >> 2) * 128 + wr * 64 + (mi & 3) * 16 + quad * 4;
    #pragma unroll
    for (int ni = 0; ni < 2 * NB; ++ni) {
      const int col = bn + (ni / NB) * (64 * NB) + wc * (16 * NB) + (ni % NB) * 16 + l16;
      const float bv = bias[col];
      #pragma unroll
      for (int r = 0; r < 4; ++r) {
        float v = acc[mi][ni][r] + bv;
        if (cmode == 0) {
          ((float*)Cout)[(size_t)(row + r) * N + col] = v;
        } else {
          const unsigned short h = f2bf_hw(v);
          const int rw = row + r;
          const int t = rw & 2047, bb = rw >> 11;
          if (col < 2048) {
            ((unsigned short*)Cout)[(size_t)rw * 2048 + col] = h;
          } else if (col < 2560) {
            // K staged: [b][kvh][d8][t][8]
            const int c2 = col - 2048, kvh = c2 >> 7, d = c2 & 127;
            kst[((((size_t)bb * 4 + kvh) * 16 + (d >> 3)) * 2048 + t) * 8 + (d & 7)] = h;
          } else {
            // V staged: [b][kvh][t8'][d][8] with sigma key-permutation:
            // slot ts = (t&~31) | ((t>>2)&3)<<3 | ((t>>4)&1)<<2 | (t&3)
            const int c2 = col - 2560, kvh = c2 >> 7, d = c2 & 127;
            const int ts = (t & ~31) | (((t >> 2) & 3) << 3) | (((t >> 4) & 1) << 2) | (t & 3);
            vst[((((size_t)bb * 4 + kvh) * 256 + (ts >> 3)) * 128 + d) * 8 + (ts & 7)] = h;
          }
        }
      }
    }
  }
  #undef LDSA_
  #undef LDSB_
  #undef KOFFA
  #undef KOFFB
  #undef STAGE_A
  #undef STAGE_B
  #undef STAGE_TILE
}

// ---------------- flash attention, GQA, causal — swapped-QK in-register softmax
// (unchanged from R10) grid (16, N_HEADS, B) = 512 x 512 threads.
__global__ __launch_bounds__(512, 4) void attn_kernel(
    const unsigned short* __restrict__ qbuf,  // (B*T, 2048) bf16 Q
    const unsigned short* __restrict__ kst,   // [b][kvh][d8][t][8]
    const unsigned short* __restrict__ vst,   // [b][kvh][t8'][d][8] (sigma-permuted)
    unsigned short* __restrict__ aout)        // (B*T, D_MODEL) bf16
{
  __shared__ __align__(16) unsigned short sK[2][16 * 64 * 8];   // per split [d8][key][8]
  __shared__ __align__(16) unsigned short sV[2][8 * 128 * 8];   // per split [t8'][d][8]

  const int tid  = threadIdx.x;
  const int wave = tid >> 6, lane = tid & 63;
  const int split = wave >> 2, g = wave & 3;
  const int quad = lane >> 4, l16 = lane & 15;
  const int head = blockIdx.y, b = blockIdx.z;
  const int kvh = head >> 2;
  const float cf = 0.08838834764831845f * 1.4426950408889634f;  // scale*log2e
  const float THR = 25.0f;  // defer-max threshold (raw S units)

  const unsigned short* kbase = kst + (size_t)((b * KV_HEADS + kvh) * 16) * 2048 * 8;
  const unsigned short* vbase = vst + (size_t)((b * KV_HEADS + kvh) * 256) * 128 * 8;

  // merge scratch overlays K/V LDS (used only after the kt loop, post-barrier)
  float* mrgO  = (float*)&sK[0][0];   // [g][d=128][q=16] f32 = 32 KB
  float* mrgML = (float*)&sV[0][0];   // [g][lane][{m,l}] f32 = 2 KB

  #define STAGE_KV(sp, kb_) do {                                               \
    _Pragma("unroll")                                                          \
    for (int it_ = 0; it_ < 4; ++it_) {                                        \
      const int c_ = it_ * 4 + g;                                              \
      __builtin_amdgcn_global_load_lds(                                        \
          (gvoid_t*)(kbase + ((size_t)c_ * 2048 + (kb_)) * 8 + lane * 8),      \
          (svoid_t*)(&sK[sp][c_ * 512]), 16, 0, 0);                            \
    }                                                                          \
    const unsigned short* vt_ = vbase + (size_t)((kb_) >> 3) * 128 * 8;        \
    _Pragma("unroll")                                                          \
    for (int it_ = 0; it_ < 4; ++it_) {                                        \
      const int c_ = it_ * 4 + g;                                              \
      __builtin_amdgcn_global_load_lds(                                        \
          (gvoid_t*)(vt_ + c_ * 512 + lane * 8),                               \
          (svoid_t*)(&sV[sp][c_ * 512]), 16, 0, 0);                            \
    }                                                                          \
  } while (0)

  #pragma unroll 1
  for (int half = 0; half < 2; ++half) {
    const int qt = half ? blockIdx.x : (31 - blockIdx.x);
    const int q0 = qt * 64;

    // Q fragments (query = q0 + g*16 + l16; B-operand role)
    shortx8 qf[4];
    {
      const unsigned short* qp = qbuf + (size_t)(b * T_SEQ + q0 + g * 16 + l16) * 2048
                                 + head * HEAD_DIM + quad * 8;
      #pragma unroll
      for (int ks = 0; ks < 4; ++ks)
        qf[ks] = *(const shortx8*)(qp + ks * 32);
    }

    float m_i = -__builtin_inff(), l_i = 0.f;
    floatx4 o_acc[8] = {};   // [nt]: O[query=l16][d = nt*16 + quad*4 + r]

    const int J = (qt >> 1) + 1;   // ceil((qt+1)/2)
    for (int j = 0; j < J; ++j) {
      const int kt = 2 * j + split;
      const bool act = (kt <= qt);
      floatx4 st[4] = {};          // st[ct][r] = S[query=l16][key=kt*64+ct*16+quad*4+r]
      unsigned int pk[4][2];       // packed bf16 P, 2 u32 per ct

      __builtin_amdgcn_s_barrier();   // A: prev iteration's LDS reads complete
      if (act) STAGE_KV(split, kt * 64);
      asm volatile("s_waitcnt vmcnt(4)" ::: "memory");  // K written; V in flight
      __builtin_amdgcn_s_barrier();   // B: K tile visible to the split's waves

      if (act) {
        // S^T = K Q^T (swapped operands; same fragments)
        __builtin_amdgcn_s_setprio(1);
        #pragma unroll
        for (int ks = 0; ks < 4; ++ks) {
          #pragma unroll
          for (int ct = 0; ct < 4; ++ct) {
            shortx8 kf = *(const shortx8*)&sK[split][((ks * 4 + quad) * 64 + ct * 16 + l16) * 8];
            st[ct] = mfma16(kf, qf[ks], st[ct]);
          }
        }
        __builtin_amdgcn_s_setprio(0);

        // causal mask on the diagonal tile
        if (kt == qt) {
          const int qrow = q0 + g * 16 + l16;
          const int kb = kt * 64;
          #pragma unroll
          for (int ct = 0; ct < 4; ++ct) {
            #pragma unroll
            for (int r = 0; r < 4; ++r)
              if (kb + ct * 16 + quad * 4 + r > qrow) st[ct][r] = -__builtin_inff();
          }
        }

        // local 16-max; defer-max: full 2-shuffle reduce only when triggered
        float lmx = -__builtin_inff();
        #pragma unroll
        for (int ct = 0; ct < 4; ++ct)
          lmx = fmaxf(lmx, fmaxf(fmaxf(st[ct][0], st[ct][1]), fmaxf(st[ct][2], st[ct][3])));
        if (__ballot(lmx > m_i + THR)) {
          float m = lmx;
          m = fmaxf(m, __shfl_xor(m, 16));
          m = fmaxf(m, __shfl_xor(m, 32));
          const float newm = fmaxf(m_i, m);
          const float alpha = exp2f((m_i - newm) * cf);
          m_i = newm;
          l_i *= alpha;
          #pragma unroll
          for (int nt = 0; nt < 8; ++nt)
            #pragma unroll
            for (int r = 0; r < 4; ++r) o_acc[nt][r] *= alpha;
        }

        // P = exp2((S - m)*cf); accumulate partial l; pack to bf16 in-register
        const float nmc = m_i * cf;
        float ps = 0.f;
        #pragma unroll
        for (int ct = 0; ct < 4; ++ct) {
          #pragma unroll
          for (int r = 0; r < 4; ++r) {
            st[ct][r] = exp2f(fmaf(st[ct][r], cf, -nmc));
            ps += st[ct][r];
          }
          pk[ct][0] = pk2bf(st[ct][0], st[ct][1]);
          pk[ct][1] = pk2bf(st[ct][2], st[ct][3]);
        }
        l_i += ps;
      }

      asm volatile("s_waitcnt vmcnt(0)" ::: "memory");  // own V writes done
      __builtin_amdgcn_s_barrier();   // C: V tile visible

      if (act) {
        // O^T += V^T P^T : A = vf (d rows), B = pa (lane-local packed P)
        #pragma unroll
        for (int kc = 0; kc < 2; ++kc) {
          union { unsigned int u[4]; shortx8 s; } pa;
          pa.u[0] = pk[2 * kc][0];     pa.u[1] = pk[2 * kc][1];
          pa.u[2] = pk[2 * kc + 1][0]; pa.u[3] = pk[2 * kc + 1][1];
          __builtin_amdgcn_s_setprio(1);
          #pragma unroll
          for (int nt = 0; nt < 8; ++nt) {
            shortx8 vf = *(const shortx8*)&sV[split][((kc * 4 + quad) * 128 + nt * 16 + l16) * 8];
            o_acc[nt] = mfma16(vf, pa.s, o_acc[nt]);
          }
          __builtin_amdgcn_s_setprio(0);
        }
      }
    }

    // ---- merge split partials, then epilogue (split0 finalizes) ----
    __builtin_amdgcn_s_barrier();   // all compute reads of K/V LDS done
    if (split == 1) {
      #pragma unroll
      for (int nt = 0; nt < 8; ++nt)
        #pragma unroll
        for (int r = 0; r < 4; ++r)
          mrgO[g * 2048 + (nt * 16 + quad * 4 + r) * 16 + l16] = o_acc[nt][r];
      mrgML[(g * 64 + lane) * 2]     = m_i;
      mrgML[(g * 64 + lane) * 2 + 1] = l_i;
    }
    asm volatile("s_waitcnt lgkmcnt(0)" ::: "memory");
    __builtin_amdgcn_s_barrier();   // partials visible

    if (split == 0) {
      const float m1 = mrgML[(g * 64 + lane) * 2];
      const float l1 = mrgML[(g * 64 + lane) * 2 + 1];
      const float M  = fmaxf(m_i, m1);
      const float a0 = exp2f((m_i - M) * cf);
      const float a1 = exp2f((m1 - M) * cf);
      float lm = a0 * l_i + a1 * l1;
      #pragma unroll
      for (int nt = 0; nt < 8; ++nt)
        #pragma unroll
        for (int r = 0; r < 4; ++r)
          o_acc[nt][r] = a0 * o_acc[nt][r]
                       + a1 * mrgO[g * 2048 + (nt * 16 + quad * 4 + r) * 16 + l16];

      lm += __shfl_xor(lm, 16);
      lm += __shfl_xor(lm, 32);
      const float inv = 1.f / lm;
      const size_t orow = (size_t)(b * T_SEQ + q0 + g * 16 + l16) * D_MODEL + head * HEAD_DIM;
      #pragma unroll
      for (int nt = 0; nt < 8; ++nt) {
        uint2 w2;
        w2.x = pk2bf(o_acc[nt][0] * inv, o_acc[nt][1] * inv);
        w2.y = pk2bf(o_acc[nt][2] * inv, o_acc[nt][3] * inv);
        *(uint2*)&aout[orow + nt * 16 + quad * 4] = w2;
      }
    }
  }
  #undef STAGE_KV
}

extern "C" void kernel_launch(void* const* d_in, const int* in_sizes, int n_in,
                              void* d_out, int out_size, void* d_ws, size_t ws_size,
                              hipStream_t stream) {
  const float* x      = (const float*)d_in[0];
  // d_in[1] = attn_mask (causal; unused)
  const float* qkv_w  = (const float*)d_in[2];
  const float* qkv_b  = (const float*)d_in[3];
  const float* proj_w = (const float*)d_in[4];
  const float* proj_b = (const float*)d_in[5];
  float* out = (float*)d_out;

  char* ws = (char*)d_ws;
  // workspace map (bytes):
  //   [0,16M)            x_bf (GEMM1 A), later attn_out
  //   [16M, 29.36M)      qkvw_t
  //   [29.36M, 37.75M)   projw_t
  //   [37.75M, 54.53M)   qbuf
  //   [54.53M, 58.72M)   kstaged
  //   [58.72M, 62.91M)   vstaged (sigma-permuted)
  unsigned short* x_bf    = (unsigned short*)(ws);
  unsigned short* qkvw_t  = (unsigned short*)(ws + (size_t)16777216);
  unsigned short* projw_t = (unsigned short*)(ws + (size_t)29360128);
  unsigned short* qbuf    = (unsigned short*)(ws + (size_t)37748736);
  unsigned short* kstaged = (unsigned short*)(ws + (size_t)54525952);
  unsigned short* vstaged = (unsigned short*)(ws + (size_t)58720256);
  unsigned short* attn_out = x_bf;   // safe alias: x_bf dead after GEMM1

  prep_kernel<<<18432, 256, 0, stream>>>(x, x_bf, qkv_w, qkvw_t, proj_w, projw_t);
  gemm256<2, 1><<<dim3(QKV_N / 256, ROWS / 256), 512, 0, stream>>>(
      x_bf, qkvw_t, qkv_b, (void*)qbuf, kstaged, vstaged, ROWS, QKV_N, D_MODEL, 2);
  attn_kernel<<<dim3(16, N_HEADS, BATCH), 512, 0, stream>>>(qbuf, kstaged, vstaged, attn_out);
  gemm256<1, 0><<<dim3(D_MODEL / 128, ROWS / 256), 512, 0, stream>>>(
      attn_out, projw_t, proj_b, (void*)out, nullptr, nullptr, ROWS, D_MODEL, D_MODEL, 0);
}